// Round 1
// baseline (587.522 us; speedup 1.0000x reference)
//
#include <hip/hip_runtime.h>
#include <hip/hip_bf16.h>
#include <cstdint>

#define HEADS 12
#define HEAD_SIZE 64
#define SEQ 512
#define HD 1024
#define NPROJ 1536   // HEADS * 2 * HEAD_SIZE
#define INF_VAL 1e13f

typedef __attribute__((ext_vector_type(8))) __bf16 bf16x8;
typedef __attribute__((ext_vector_type(4))) float f32x4;

__device__ __forceinline__ unsigned short f2bf(float f) {
    unsigned u = __float_as_uint(f);
    u += 0x7fffu + ((u >> 16) & 1u);   // RNE
    return (unsigned short)(u >> 16);
}

// ---------------------------------------------------------------------------
// Kernel 1: W (1024 x 1536 f32, row-major) -> Wt (1536 x 1024 bf16)
// ---------------------------------------------------------------------------
__global__ void __launch_bounds__(256) transpose_cast_w(const float* __restrict__ W,
                                                        unsigned short* __restrict__ Wt) {
    __shared__ unsigned short tile[64][65];
    const int bx = blockIdx.x;
    const int k0 = (bx & 15) * 64;   // 16 k-tiles
    const int n0 = (bx >> 4) * 64;   // 24 n-tiles
    const int t = threadIdx.x;
    const int tr = t >> 4;           // 0..15
    const int tc = (t & 15) * 4;     // 0..60
#pragma unroll
    for (int i = 0; i < 4; ++i) {
        int kk = tr + i * 16;
        float4 v = *(const float4*)&W[(size_t)(k0 + kk) * NPROJ + n0 + tc];
        tile[kk][tc + 0] = f2bf(v.x);
        tile[kk][tc + 1] = f2bf(v.y);
        tile[kk][tc + 2] = f2bf(v.z);
        tile[kk][tc + 3] = f2bf(v.w);
    }
    __syncthreads();
#pragma unroll
    for (int i = 0; i < 4; ++i) {
        int nn = tr + i * 16;
        ushort4 o;
        o.x = tile[tc + 0][nn];
        o.y = tile[tc + 1][nn];
        o.z = tile[tc + 2][nn];
        o.w = tile[tc + 3][nn];
        *(ushort4*)&Wt[(size_t)(n0 + nn) * HD + k0 + tc] = o;
    }
}

// ---------------------------------------------------------------------------
// Kernel 2: proj = x @ W + b, fused RoPE, writes q/k bf16 in (B,H,S,D) layout.
// Tile: 128(m) x 128(n).  n-tile == one head (q cols 0..63, k cols 64..127).
// 4 waves in 2x2; each wave 64x64 via 4x4 of 16x16x32 bf16 MFMA.
// ---------------------------------------------------------------------------
__global__ void __launch_bounds__(256) gemm1_rope(const float* __restrict__ x,
                                                  const unsigned short* __restrict__ Wt,
                                                  const float* __restrict__ bias,
                                                  unsigned short* __restrict__ qws,
                                                  unsigned short* __restrict__ kws) {
    __shared__ __align__(16) char smem[32768];
    unsigned short* Alds = (unsigned short*)smem;            // 128 rows, stride 40 elems
    unsigned short* Blds = (unsigned short*)(smem + 10240);  // 128 rows, stride 40 elems

    const int bx = blockIdx.x;              // tile_m * 12 + h  (h minor -> L2 A-reuse)
    const int tile_m = bx / HEADS;
    const int h = bx - tile_m * HEADS;
    const int m0 = tile_m * 128;
    const int n0 = h * 128;

    const int t = threadIdx.x;
    const int w = t >> 6;
    const int lane = t & 63;
    const int wm = w >> 1;          // 0..1
    const int wn = w & 1;           // 0 -> q half, 1 -> k half
    const int c16 = lane & 15;
    const int quad = lane >> 4;

    const int sr = t >> 1;          // staging row 0..127
    const int sc = (t & 1) * 16;    // staging col offset (elems)

    f32x4 acc[4][4];
#pragma unroll
    for (int i = 0; i < 4; ++i)
#pragma unroll
        for (int j = 0; j < 4; ++j) acc[i][j] = (f32x4){0.f, 0.f, 0.f, 0.f};

    const float* xrow = x + (size_t)(m0 + sr) * HD + sc;
    const unsigned short* wrow = Wt + (size_t)(n0 + sr) * HD + sc;

    for (int kt = 0; kt < HD; kt += 32) {
        // stage A (fp32 -> bf16): 16 floats / thread
        float4 v0 = *(const float4*)(xrow + kt + 0);
        float4 v1 = *(const float4*)(xrow + kt + 4);
        float4 v2 = *(const float4*)(xrow + kt + 8);
        float4 v3 = *(const float4*)(xrow + kt + 12);
        uint4 p0, p1;
        p0.x = f2bf(v0.x) | ((unsigned)f2bf(v0.y) << 16);
        p0.y = f2bf(v0.z) | ((unsigned)f2bf(v0.w) << 16);
        p0.z = f2bf(v1.x) | ((unsigned)f2bf(v1.y) << 16);
        p0.w = f2bf(v1.z) | ((unsigned)f2bf(v1.w) << 16);
        p1.x = f2bf(v2.x) | ((unsigned)f2bf(v2.y) << 16);
        p1.y = f2bf(v2.z) | ((unsigned)f2bf(v2.w) << 16);
        p1.z = f2bf(v3.x) | ((unsigned)f2bf(v3.y) << 16);
        p1.w = f2bf(v3.z) | ((unsigned)f2bf(v3.w) << 16);
        *(uint4*)((char*)Alds + sr * 80 + sc * 2) = p0;
        *(uint4*)((char*)Alds + sr * 80 + sc * 2 + 16) = p1;
        // stage B (already bf16): 16 elems / thread
        const uint4* bsrc = (const uint4*)(wrow + kt);
        *(uint4*)((char*)Blds + sr * 80 + sc * 2) = bsrc[0];
        *(uint4*)((char*)Blds + sr * 80 + sc * 2 + 16) = bsrc[1];
        __syncthreads();

        bf16x8 af[4], bfr[4];
#pragma unroll
        for (int mi = 0; mi < 4; ++mi)
            af[mi] = *(const bf16x8*)((char*)Alds + (wm * 64 + mi * 16 + c16) * 80 + quad * 16);
#pragma unroll
        for (int ni = 0; ni < 4; ++ni)
            bfr[ni] = *(const bf16x8*)((char*)Blds + (wn * 64 + ni * 16 + c16) * 80 + quad * 16);
#pragma unroll
        for (int mi = 0; mi < 4; ++mi)
#pragma unroll
            for (int ni = 0; ni < 4; ++ni)
                acc[mi][ni] = __builtin_amdgcn_mfma_f32_16x16x32_bf16(af[mi], bfr[ni], acc[mi][ni], 0, 0, 0);
        __syncthreads();
    }

    // bias per output column
    float bv[4];
#pragma unroll
    for (int ni = 0; ni < 4; ++ni) bv[ni] = bias[n0 + wn * 64 + ni * 16 + c16];

    // build sin/cos table for this tile's 128 positions x 32 freqs (aliases staging LDS)
    float2* tab = (float2*)smem;
    const int sbase = m0 & (SEQ - 1);
#pragma unroll
    for (int i = 0; i < 16; ++i) {
        int e = t * 16 + i;
        int srow = e >> 5;
        int fi = e & 31;
        float invf = __expf(-(float)fi * (0.03125f * 9.210340371976184f)); // 10000^(-fi/32)
        float theta = (float)(sbase + srow) * invf;
        float sv, cv;
        __sincosf(theta, &sv, &cv);
        tab[e] = make_float2(sv, cv);
    }
    __syncthreads();

    unsigned short* outp = wn ? kws : qws;
#pragma unroll
    for (int mi = 0; mi < 4; ++mi) {
#pragma unroll
        for (int ni = 0; ni < 4; ++ni) {
            int d = ni * 16 + c16;       // 0..63 within this head's q (or k)
            int fi = d >> 1;
            float sgn = (d & 1) ? 1.f : -1.f;
#pragma unroll
            for (int r = 0; r < 4; ++r) {
                float v = acc[mi][ni][r] + bv[ni];
                float p = __shfl_xor(v, 1, 64);  // partner element of the RoPE pair
                int srow = wm * 64 + mi * 16 + quad * 4 + r;
                float2 sc2 = tab[srow * 32 + fi];
                float o = v * sc2.y + sgn * p * sc2.x;  // even: v*c - p*s ; odd: v*c + p*s
                int m = m0 + srow;
                int bb = m >> 9;
                int ss = m & (SEQ - 1);
                outp[((size_t)(bb * HEADS + h) * SEQ + ss) * HEAD_SIZE + d] = f2bf(o);
            }
        }
    }
}

// ---------------------------------------------------------------------------
// Kernel 3: logits[b,h,m,n] = (q[bh,m,:].k[bh,n,:] - (pad+tril)*INF) / 8
// Tile 128x128 per block, K=64 staged once. LDS rows padded to 72 elems.
// ---------------------------------------------------------------------------
__global__ void __launch_bounds__(256) gemm2_mask(const unsigned short* __restrict__ qws,
                                                  const unsigned short* __restrict__ kws,
                                                  const int* __restrict__ am,
                                                  float* __restrict__ out) {
    __shared__ __align__(16) unsigned short qlds[128 * 72];
    __shared__ __align__(16) unsigned short klds[128 * 72];
    const int bh = blockIdx.y;
    const int b = bh / HEADS;
    const int tm = (blockIdx.x >> 2) * 128;
    const int tn = (blockIdx.x & 3) * 128;
    const int t = threadIdx.x;
    const int w = t >> 6, lane = t & 63;
    const int wm = w >> 1, wn = w & 1;
    const int c16 = lane & 15, quad = lane >> 4;

    // stage q & k tiles: each thread copies 64 contiguous bytes per tile
    {
        const int sr = t >> 1;
        const int sc = (t & 1) * 32;  // elems
        const uint4* src = (const uint4*)(qws + ((size_t)bh * SEQ + tm + sr) * HEAD_SIZE + sc);
        uint4* dst = (uint4*)((char*)qlds + sr * 144 + sc * 2);
        dst[0] = src[0]; dst[1] = src[1]; dst[2] = src[2]; dst[3] = src[3];
        const uint4* src2 = (const uint4*)(kws + ((size_t)bh * SEQ + tn + sr) * HEAD_SIZE + sc);
        uint4* dst2 = (uint4*)((char*)klds + sr * 144 + sc * 2);
        dst2[0] = src2[0]; dst2[1] = src2[1]; dst2[2] = src2[2]; dst2[3] = src2[3];
    }
    __syncthreads();

    f32x4 acc[4][4];
#pragma unroll
    for (int i = 0; i < 4; ++i)
#pragma unroll
        for (int j = 0; j < 4; ++j) acc[i][j] = (f32x4){0.f, 0.f, 0.f, 0.f};

#pragma unroll
    for (int ks = 0; ks < 2; ++ks) {
        bf16x8 af[4], bfr[4];
#pragma unroll
        for (int mi = 0; mi < 4; ++mi)
            af[mi] = *(const bf16x8*)((char*)qlds + (wm * 64 + mi * 16 + c16) * 144 + ks * 64 + quad * 16);
#pragma unroll
        for (int ni = 0; ni < 4; ++ni)
            bfr[ni] = *(const bf16x8*)((char*)klds + (wn * 64 + ni * 16 + c16) * 144 + ks * 64 + quad * 16);
#pragma unroll
        for (int mi = 0; mi < 4; ++mi)
#pragma unroll
            for (int ni = 0; ni < 4; ++ni)
                acc[mi][ni] = __builtin_amdgcn_mfma_f32_16x16x32_bf16(af[mi], bfr[ni], acc[mi][ni], 0, 0, 0);
    }

    const int* amb = am + b * SEQ;
    float amn[4];
#pragma unroll
    for (int ni = 0; ni < 4; ++ni) amn[ni] = (float)amb[tn + wn * 64 + ni * 16 + c16];
#pragma unroll
    for (int mi = 0; mi < 4; ++mi) {
#pragma unroll
        for (int r = 0; r < 4; ++r) {
            int m = tm + wm * 64 + mi * 16 + quad * 4 + r;
            float amm = (float)amb[m];
#pragma unroll
            for (int ni = 0; ni < 4; ++ni) {
                int n = tn + wn * 64 + ni * 16 + c16;
                float pen = (1.0f - amm * amn[ni]) + ((m > n) ? 1.0f : 0.0f);
                out[((size_t)bh * SEQ + m) * SEQ + n] = (acc[mi][ni][r] - pen * INF_VAL) * 0.125f;
            }
        }
    }
}

extern "C" void kernel_launch(void* const* d_in, const int* in_sizes, int n_in,
                              void* d_out, int out_size, void* d_ws, size_t ws_size,
                              hipStream_t stream) {
    (void)in_sizes; (void)n_in; (void)out_size; (void)ws_size;
    const float* x = (const float*)d_in[0];
    const float* W = (const float*)d_in[1];
    const float* bias = (const float*)d_in[2];
    const int* am = (const int*)d_in[3];
    float* out = (float*)d_out;

    // workspace layout
    unsigned short* Wt = (unsigned short*)d_ws;                              // 1536*1024*2  = 3 MiB
    unsigned short* qws = (unsigned short*)((char*)d_ws + 3145728);          // 32*12*512*64*2 = 24 MiB
    unsigned short* kws = (unsigned short*)((char*)d_ws + 3145728 + 25165824);

    hipLaunchKernelGGL(transpose_cast_w, dim3(384), dim3(256), 0, stream, W, Wt);
    hipLaunchKernelGGL(gemm1_rope, dim3(128 * HEADS), dim3(256), 0, stream, x, Wt, bias, qws, kws);
    hipLaunchKernelGGL(gemm2_mask, dim3(16, 32 * HEADS), dim3(256), 0, stream, qws, kws, am, out);
}

// Round 2
// 549.427 us; speedup vs baseline: 1.0693x; 1.0693x over previous
//
#include <hip/hip_runtime.h>
#include <hip/hip_bf16.h>
#include <cstdint>

#define HEADS 12
#define HEAD_SIZE 64
#define SEQ 512
#define HD 1024
#define NPROJ 1536   // HEADS * 2 * HEAD_SIZE
#define INF_VAL 1e13f

typedef __attribute__((ext_vector_type(8))) __bf16 bf16x8;
typedef __attribute__((ext_vector_type(4))) float f32x4;

__device__ __forceinline__ unsigned short f2bf(float f) {
    unsigned u = __float_as_uint(f);
    u += 0x7fffu + ((u >> 16) & 1u);   // RNE
    return (unsigned short)(u >> 16);
}

// async global -> LDS, 16B per lane, lane-ordered contiguous LDS destination
__device__ __forceinline__ void gl_lds16(const unsigned short* g, unsigned short* l) {
    __builtin_amdgcn_global_load_lds(
        (const __attribute__((address_space(1))) unsigned int*)g,
        (__attribute__((address_space(3))) unsigned int*)l, 16, 0, 0);
}

// ---------------------------------------------------------------------------
// Kernel 0: x (f32) -> xb (bf16), flat cast. 16,777,216 elems, 8 per thread.
// ---------------------------------------------------------------------------
__global__ void __launch_bounds__(256) convert_x(const float* __restrict__ x,
                                                 unsigned short* __restrict__ xb) {
    const int i = blockIdx.x * 256 + threadIdx.x;
    const float4* src = (const float4*)x;
    float4 v0 = src[i * 2 + 0];
    float4 v1 = src[i * 2 + 1];
    uint4 p;
    p.x = f2bf(v0.x) | ((unsigned)f2bf(v0.y) << 16);
    p.y = f2bf(v0.z) | ((unsigned)f2bf(v0.w) << 16);
    p.z = f2bf(v1.x) | ((unsigned)f2bf(v1.y) << 16);
    p.w = f2bf(v1.z) | ((unsigned)f2bf(v1.w) << 16);
    ((uint4*)xb)[i] = p;
}

// ---------------------------------------------------------------------------
// Kernel 1: W (1024 x 1536 f32, row-major) -> Wt (1536 x 1024 bf16)
// ---------------------------------------------------------------------------
__global__ void __launch_bounds__(256) transpose_cast_w(const float* __restrict__ W,
                                                        unsigned short* __restrict__ Wt) {
    __shared__ unsigned short tile[64][65];
    const int bx = blockIdx.x;
    const int k0 = (bx & 15) * 64;   // 16 k-tiles
    const int n0 = (bx >> 4) * 64;   // 24 n-tiles
    const int t = threadIdx.x;
    const int tr = t >> 4;           // 0..15
    const int tc = (t & 15) * 4;     // 0..60
#pragma unroll
    for (int i = 0; i < 4; ++i) {
        int kk = tr + i * 16;
        float4 v = *(const float4*)&W[(size_t)(k0 + kk) * NPROJ + n0 + tc];
        tile[kk][tc + 0] = f2bf(v.x);
        tile[kk][tc + 1] = f2bf(v.y);
        tile[kk][tc + 2] = f2bf(v.z);
        tile[kk][tc + 3] = f2bf(v.w);
    }
    __syncthreads();
#pragma unroll
    for (int i = 0; i < 4; ++i) {
        int nn = tr + i * 16;
        ushort4 o;
        o.x = tile[tc + 0][nn];
        o.y = tile[tc + 1][nn];
        o.z = tile[tc + 2][nn];
        o.w = tile[tc + 3][nn];
        *(ushort4*)&Wt[(size_t)(n0 + nn) * HD + k0 + tc] = o;
    }
}

// ---------------------------------------------------------------------------
// Kernel 2: proj = xb @ Wt^T + b, fused RoPE, writes q/k bf16 in (B,H,S,D).
// m97 structure: 128x128 tile, BK=32, unpadded 128x32 bf16 LDS tiles,
// global_load_lds width=16, 2-barrier K-loop. 4 waves in 2x2.
// ---------------------------------------------------------------------------
__global__ void __launch_bounds__(256) gemm1_rope(const unsigned short* __restrict__ xb,
                                                  const unsigned short* __restrict__ Wt,
                                                  const float* __restrict__ bias,
                                                  unsigned short* __restrict__ qws,
                                                  unsigned short* __restrict__ kws) {
    __shared__ __align__(16) char smem[32768];
    unsigned short* Alds = (unsigned short*)smem;            // 128 x 32 bf16, 64B rows, NO pad
    unsigned short* Blds = (unsigned short*)(smem + 8192);   // 128 x 32 bf16

    const int bx = blockIdx.x;              // tile_m * 12 + h
    const int tile_m = bx / HEADS;
    const int h = bx - tile_m * HEADS;
    const int m0 = tile_m * 128;
    const int n0 = h * 128;

    const int t = threadIdx.x;
    const int w = t >> 6;
    const int lane = t & 63;
    const int wm = w >> 1;          // 0..1
    const int wn = w & 1;           // 0 -> q half, 1 -> k half
    const int c16 = lane & 15;
    const int quad = lane >> 4;

    // staging coords: inst j covers LDS bytes [w*2048 + j*1024, +1024), lane*16 within.
    // row = w*32 + j*16 + lane/4, col elem = (lane&3)*8.  (byte off == w*2048+j*1024+lane*16)
    const int row0 = w * 32 + (lane >> 2);
    const int celem = (lane & 3) * 8;
    const unsigned short* ga0 = xb + (size_t)(m0 + row0) * HD + celem;
    const unsigned short* ga1 = xb + (size_t)(m0 + row0 + 16) * HD + celem;
    const unsigned short* gb0 = Wt + (size_t)(n0 + row0) * HD + celem;
    const unsigned short* gb1 = Wt + (size_t)(n0 + row0 + 16) * HD + celem;
    unsigned short* la0 = Alds + row0 * 32 + celem;
    unsigned short* la1 = Alds + (row0 + 16) * 32 + celem;
    unsigned short* lb0 = Blds + row0 * 32 + celem;
    unsigned short* lb1 = Blds + (row0 + 16) * 32 + celem;

    f32x4 acc[4][4];
#pragma unroll
    for (int i = 0; i < 4; ++i)
#pragma unroll
        for (int j = 0; j < 4; ++j) acc[i][j] = (f32x4){0.f, 0.f, 0.f, 0.f};

    for (int kt = 0; kt < HD; kt += 32) {
        gl_lds16(ga0 + kt, la0);
        gl_lds16(ga1 + kt, la1);
        gl_lds16(gb0 + kt, lb0);
        gl_lds16(gb1 + kt, lb1);
        __syncthreads();   // drains vmcnt (global_load_lds) before reads

        bf16x8 af[4], bfr[4];
#pragma unroll
        for (int mi = 0; mi < 4; ++mi)
            af[mi] = *(const bf16x8*)((char*)Alds + (wm * 64 + mi * 16 + c16) * 64 + quad * 16);
#pragma unroll
        for (int ni = 0; ni < 4; ++ni)
            bfr[ni] = *(const bf16x8*)((char*)Blds + (wn * 64 + ni * 16 + c16) * 64 + quad * 16);
#pragma unroll
        for (int mi = 0; mi < 4; ++mi)
#pragma unroll
            for (int ni = 0; ni < 4; ++ni)
                acc[mi][ni] = __builtin_amdgcn_mfma_f32_16x16x32_bf16(af[mi], bfr[ni], acc[mi][ni], 0, 0, 0);
        __syncthreads();   // before next iter overwrites LDS
    }

    // bias per output column
    float bv[4];
#pragma unroll
    for (int ni = 0; ni < 4; ++ni) bv[ni] = bias[n0 + wn * 64 + ni * 16 + c16];

    // sin/cos table: 128 positions x 32 freqs (float2) = 32 KB, aliases staging LDS
    float2* tab = (float2*)smem;
    const int sbase = m0 & (SEQ - 1);
#pragma unroll
    for (int i = 0; i < 16; ++i) {
        int e = t * 16 + i;
        int srow = e >> 5;
        int fi = e & 31;
        float invf = __expf(-(float)fi * (0.03125f * 9.210340371976184f)); // 10000^(-fi/32)
        float theta = (float)(sbase + srow) * invf;
        float sv, cv;
        __sincosf(theta, &sv, &cv);
        tab[e] = make_float2(sv, cv);
    }
    __syncthreads();

    unsigned short* outp = wn ? kws : qws;
#pragma unroll
    for (int mi = 0; mi < 4; ++mi) {
#pragma unroll
        for (int ni = 0; ni < 4; ++ni) {
            int d = ni * 16 + c16;       // 0..63 within this head's q (or k)
            int fi = d >> 1;
            float sgn = (d & 1) ? 1.f : -1.f;
#pragma unroll
            for (int r = 0; r < 4; ++r) {
                float v = acc[mi][ni][r] + bv[ni];
                float p = __shfl_xor(v, 1, 64);  // RoPE pair partner
                int srow = wm * 64 + mi * 16 + quad * 4 + r;
                float2 sc2 = tab[srow * 32 + fi];
                float o = v * sc2.y + sgn * p * sc2.x;  // even: v*c - p*s ; odd: v*c + p*s
                int m = m0 + srow;
                int bb = m >> 9;
                int ss = m & (SEQ - 1);
                outp[((size_t)(bb * HEADS + h) * SEQ + ss) * HEAD_SIZE + d] = f2bf(o);
            }
        }
    }
}

// ---------------------------------------------------------------------------
// Kernel 3: logits[b,h,m,n] = (q[bh,m,:].k[bh,n,:] - (pad+tril)*INF) / 8
// Tile 128x128 per block, K=64 staged once. LDS rows padded to 72 elems.
// ---------------------------------------------------------------------------
__global__ void __launch_bounds__(256) gemm2_mask(const unsigned short* __restrict__ qws,
                                                  const unsigned short* __restrict__ kws,
                                                  const int* __restrict__ am,
                                                  float* __restrict__ out) {
    __shared__ __align__(16) unsigned short qlds[128 * 72];
    __shared__ __align__(16) unsigned short klds[128 * 72];
    const int bh = blockIdx.y;
    const int b = bh / HEADS;
    const int tm = (blockIdx.x >> 2) * 128;
    const int tn = (blockIdx.x & 3) * 128;
    const int t = threadIdx.x;
    const int w = t >> 6, lane = t & 63;
    const int wm = w >> 1, wn = w & 1;
    const int c16 = lane & 15, quad = lane >> 4;

    {
        const int sr = t >> 1;
        const int sc = (t & 1) * 32;  // elems
        const uint4* src = (const uint4*)(qws + ((size_t)bh * SEQ + tm + sr) * HEAD_SIZE + sc);
        uint4* dst = (uint4*)((char*)qlds + sr * 144 + sc * 2);
        dst[0] = src[0]; dst[1] = src[1]; dst[2] = src[2]; dst[3] = src[3];
        const uint4* src2 = (const uint4*)(kws + ((size_t)bh * SEQ + tn + sr) * HEAD_SIZE + sc);
        uint4* dst2 = (uint4*)((char*)klds + sr * 144 + sc * 2);
        dst2[0] = src2[0]; dst2[1] = src2[1]; dst2[2] = src2[2]; dst2[3] = src2[3];
    }
    __syncthreads();

    f32x4 acc[4][4];
#pragma unroll
    for (int i = 0; i < 4; ++i)
#pragma unroll
        for (int j = 0; j < 4; ++j) acc[i][j] = (f32x4){0.f, 0.f, 0.f, 0.f};

#pragma unroll
    for (int ks = 0; ks < 2; ++ks) {
        bf16x8 af[4], bfr[4];
#pragma unroll
        for (int mi = 0; mi < 4; ++mi)
            af[mi] = *(const bf16x8*)((char*)qlds + (wm * 64 + mi * 16 + c16) * 144 + ks * 64 + quad * 16);
#pragma unroll
        for (int ni = 0; ni < 4; ++ni)
            bfr[ni] = *(const bf16x8*)((char*)klds + (wn * 64 + ni * 16 + c16) * 144 + ks * 64 + quad * 16);
#pragma unroll
        for (int mi = 0; mi < 4; ++mi)
#pragma unroll
            for (int ni = 0; ni < 4; ++ni)
                acc[mi][ni] = __builtin_amdgcn_mfma_f32_16x16x32_bf16(af[mi], bfr[ni], acc[mi][ni], 0, 0, 0);
    }

    const int* amb = am + b * SEQ;
    float amn[4];
#pragma unroll
    for (int ni = 0; ni < 4; ++ni) amn[ni] = (float)amb[tn + wn * 64 + ni * 16 + c16];
#pragma unroll
    for (int mi = 0; mi < 4; ++mi) {
#pragma unroll
        for (int r = 0; r < 4; ++r) {
            int m = tm + wm * 64 + mi * 16 + quad * 4 + r;
            float amm = (float)amb[m];
#pragma unroll
            for (int ni = 0; ni < 4; ++ni) {
                int n = tn + wn * 64 + ni * 16 + c16;
                float pen = (1.0f - amm * amn[ni]) + ((m > n) ? 1.0f : 0.0f);
                out[((size_t)bh * SEQ + m) * SEQ + n] = (acc[mi][ni][r] - pen * INF_VAL) * 0.125f;
            }
        }
    }
}

extern "C" void kernel_launch(void* const* d_in, const int* in_sizes, int n_in,
                              void* d_out, int out_size, void* d_ws, size_t ws_size,
                              hipStream_t stream) {
    (void)in_sizes; (void)n_in; (void)out_size; (void)ws_size;
    const float* x = (const float*)d_in[0];
    const float* W = (const float*)d_in[1];
    const float* bias = (const float*)d_in[2];
    const int* am = (const int*)d_in[3];
    float* out = (float*)d_out;

    // workspace layout
    unsigned short* Wt  = (unsigned short*)d_ws;                                // 3 MiB
    unsigned short* qws = (unsigned short*)((char*)d_ws + 3145728);             // 24 MiB
    unsigned short* kws = (unsigned short*)((char*)d_ws + 3145728 + 25165824);  // 24 MiB
    unsigned short* xb  = (unsigned short*)((char*)d_ws + 3145728 + 2 * 25165824); // 32 MiB

    hipLaunchKernelGGL(convert_x, dim3(8192), dim3(256), 0, stream, x, xb);
    hipLaunchKernelGGL(transpose_cast_w, dim3(384), dim3(256), 0, stream, W, Wt);
    hipLaunchKernelGGL(gemm1_rope, dim3(128 * HEADS), dim3(256), 0, stream, xb, Wt, bias, qws, kws);
    hipLaunchKernelGGL(gemm2_mask, dim3(16, 32 * HEADS), dim3(256), 0, stream, qws, kws, am, out);
}